// Round 13
// baseline (174.473 us; speedup 1.0000x reference)
//
#include <hip/hip_runtime.h>
#include <hip/hip_bf16.h>

typedef unsigned short u16;
typedef short bf16x8 __attribute__((ext_vector_type(8)));
typedef float f32x4 __attribute__((ext_vector_type(4)));

#define NXC 768
#define NHEAD 12
#define SEQ 2048
#define BSZ 2
#define HD 64
#define NCHUNK 40   // sum over 16 q-tiles of ceil(128*(bx+1)/512)
#define LOG2E 1.4426950408889634f

__device__ inline u16 f2bf(float f) {
    unsigned int u = __float_as_uint(f);
    unsigned int r = u + 0x7fffu + ((u >> 16) & 1u);
    return (u16)(r >> 16);
}
__device__ inline unsigned pk2(float lo, float hi) {
    return (unsigned)f2bf(lo) | ((unsigned)f2bf(hi) << 16);
}
__device__ inline float ex2(float x) { return __builtin_amdgcn_exp2f(x); }

// async global->LDS, 16B per lane. LDS dest is wave-uniform base + lane*16.
__device__ inline void gld16(const u16* g, u16* l) {
    __builtin_amdgcn_global_load_lds(
        (const __attribute__((address_space(1))) unsigned int*)(g),
        (__attribute__((address_space(3))) unsigned int*)(l),
        16, 0, 0);
}

// ---------------- merged prep: cast HS + transpose-cast both weights --------
// grid 5376 x 256: blocks [0,3072) cast4, [3072,4800) w_attn^T, [4800,5376) w_proj^T
__global__ __launch_bounds__(256) void prep_kernel(
    const float* __restrict__ hs, u16* __restrict__ HSbf,
    const float* __restrict__ w_attn, u16* __restrict__ WaT,
    const float* __restrict__ w_proj, u16* __restrict__ WpT) {
    __shared__ float tile[32][33];
    int blk = blockIdx.x;
    int t = threadIdx.x;
    if (blk < 3072) {                       // cast: 786432 float4s
        int i = blk * 256 + t;
        float4 v = ((const float4*)hs)[i];
        ushort4 o;
        o.x = f2bf(v.x); o.y = f2bf(v.y); o.z = f2bf(v.z); o.w = f2bf(v.w);
        ((ushort4*)HSbf)[i] = o;
        return;
    }
    const float* in; u16* out; int C, cb, rb;
    if (blk < 4800) {                       // w_attn: 2304 cols x 768 rows
        int idx = blk - 3072;
        in = w_attn; out = WaT; C = 3 * NXC;
        cb = (idx % 72) * 32; rb = (idx / 72) * 32;
    } else {                                // w_proj: 768 x 768
        int idx = blk - 4800;
        in = w_proj; out = WpT; C = NXC;
        cb = (idx % 24) * 32; rb = (idx / 24) * 32;
    }
    int tx = t & 31, ty = t >> 5;           // (32,8) decomposition
    #pragma unroll
    for (int i = 0; i < 32; i += 8)
        tile[ty + i][tx] = in[(size_t)(rb + ty + i) * C + cb + tx];
    __syncthreads();
    #pragma unroll
    for (int i = 0; i < 32; i += 8)
        out[(size_t)(cb + ty + i) * NXC + rb + tx] = f2bf(tile[tx][ty + i]);
}

// per-head transpose: Vb head-chunk [ss][dd] -> Vtg [dd][ss] (both bf16).
// NOTE: interprets Vb's flat memory as [b*12+h][s][d] — matches the
// reference's DIRECT reshape semantics. Do not fuse into the GEMM epilogue.
__global__ __launch_bounds__(256) void vt_kernel(const u16* __restrict__ Vb,
                                                 u16* __restrict__ Vtg) {
    __shared__ u16 tile[64][68];
    int y = blockIdx.y;                        // b*NHEAD+h
    size_t base = (size_t)y * (SEQ * HD);
    int ss0 = blockIdx.x * 64;
    int t = threadIdx.x;
    #pragma unroll
    for (int c = t; c < 512; c += 256) {
        int r = c >> 3, col = (c & 7) * 8;
        *(uint4*)&tile[r][col] = *(const uint4*)&Vb[base + (size_t)(ss0 + r) * HD + col];
    }
    __syncthreads();
    #pragma unroll
    for (int c = t; c < 512; c += 256) {
        int dd = c >> 3, s8 = (c & 7) * 8;
        ushort4 a, bq;
        a.x = tile[s8 + 0][dd]; a.y = tile[s8 + 1][dd];
        a.z = tile[s8 + 2][dd]; a.w = tile[s8 + 3][dd];
        bq.x = tile[s8 + 4][dd]; bq.y = tile[s8 + 5][dd];
        bq.z = tile[s8 + 6][dd]; bq.w = tile[s8 + 7][dd];
        u16* dst = &Vtg[base + (size_t)dd * SEQ + ss0 + s8];
        *(ushort4*)dst = a;
        *(ushort4*)(dst + 4) = bq;
    }
}

// ---------------- GEMM: C[M][N] = A[M][K] * BT[N][K]^T + bias ----------------
// 128x128 tile, BK=32, 256 threads = 4 waves (2x2), each wave owns 64x64
// (4x4 16x16x32 frags, 16 MFMA per K-step). global_load_lds dwordx4 into a
// TRIPLE LDS buffer with prefetch depth 2 and counted s_waitcnt vmcnt(8).
// XCD-AWARE BLOCK SWIZZLE (T1, measured -2.9us r10): each XCD owns a
// contiguous (numN/2) x (numM/4) tile region so its operand panels
// (~3.3MB gemm0 / ~2.2MB gemm1) fit the 4MB per-XCD L2.
// EPI 0: bf16 Q, K (pre-scaled 0.125*log2e), V natural. EPI 1: fp32 out.
template <int EPI>
__global__ __launch_bounds__(256) void gemm_bt_kernel(
    const u16* __restrict__ A, const u16* __restrict__ BT,
    const float* __restrict__ bias,
    u16* __restrict__ outQ, u16* __restrict__ outK, u16* __restrict__ outV,
    float* __restrict__ outF,
    int M, int N, int K) {
    __shared__ u16 As[3 * 128 * 32];
    __shared__ u16 Bs[3 * 128 * 32];
    int numN = N >> 7, numM = M >> 7;
    int nPer = numN >> 1, mPer = numM >> 2;    // 2(N) x 4(M) XCD split
    int wgid = blockIdx.x;
    int xcd = wgid & 7, local = wgid >> 3;
    int nloc = local % nPer, mloc = local / nPer;
    int tileN = (((xcd & 1) * nPer) + nloc) << 7;
    int tileM = ((((xcd >> 1) & 3) * mPer) + mloc) << 7;
    int t = threadIdx.x;
    int lane = t & 63, wave = t >> 6;
    int wr = (wave >> 1) * 64, wc = (wave & 1) * 64;   // wave's 64x64 sub-tile
    int quad = lane >> 4, l16 = lane & 15;
    f32x4 acc[4][4] = {};

    int r0 = t >> 2, c0 = (t & 3) * 8;
    const u16* Ag0 = A + (size_t)(tileM + r0) * K + c0;
    const u16* Ag1 = Ag0 + (size_t)64 * K;
    const u16* Bg0 = BT + (size_t)(tileN + r0) * K + c0;
    const u16* Bg1 = Bg0 + (size_t)64 * K;
    u16* AsW0 = As + wave * 512;           // rows 0..63 half
    u16* AsW1 = As + 2048 + wave * 512;    // rows 64..127 half
    u16* BsW0 = Bs + wave * 512;
    u16* BsW1 = Bs + 2048 + wave * 512;

    // prologue: stage tiles 0 and 1 into buffers 0 and 1
    gld16(Ag0, AsW0);
    gld16(Ag1, AsW1);
    gld16(Bg0, BsW0);
    gld16(Bg1, BsW1);
    gld16(Ag0 + 32, AsW0 + 4096);
    gld16(Ag1 + 32, AsW1 + 4096);
    gld16(Bg0 + 32, BsW0 + 4096);
    gld16(Bg1 + 32, BsW1 + 4096);

    int NT = K >> 5;                       // 24 for K=768
    for (int tt = 0; tt < NT; ++tt) {
        int cur = tt % 3;
        if (tt + 2 < NT) {
            int kn = (tt + 2) * 32;
            int nb = ((tt + 2) % 3) * 4096;
            gld16(Ag0 + kn, AsW0 + nb);
            gld16(Ag1 + kn, AsW1 + nb);
            gld16(Bg0 + kn, BsW0 + nb);
            gld16(Bg1 + kn, BsW1 + nb);
            asm volatile("s_waitcnt vmcnt(8)" ::: "memory");  // tile tt landed
        } else if (tt + 1 < NT) {
            asm volatile("s_waitcnt vmcnt(4)" ::: "memory");  // tile tt landed
        } else {
            asm volatile("s_waitcnt vmcnt(0)" ::: "memory");
        }
        __builtin_amdgcn_s_barrier();          // all waves' tile-tt stage landed
        __builtin_amdgcn_sched_barrier(0);     // nothing moves above the barrier

        const u16* Ac = As + cur * 4096;
        const u16* Bc = Bs + cur * 4096;
        bf16x8 af[4], bfr[4];
        #pragma unroll
        for (int i = 0; i < 4; ++i)
            af[i] = *(const bf16x8*)&Ac[(wr + i * 16 + l16) * 32 + quad * 8];
        #pragma unroll
        for (int j = 0; j < 4; ++j)
            bfr[j] = *(const bf16x8*)&Bc[(wc + j * 16 + l16) * 32 + quad * 8];
        #pragma unroll
        for (int i = 0; i < 4; ++i)
            #pragma unroll
            for (int j = 0; j < 4; ++j)
                acc[i][j] = __builtin_amdgcn_mfma_f32_16x16x32_bf16(af[i], bfr[j], acc[i][j], 0, 0, 0);

        __builtin_amdgcn_sched_barrier(0);     // ds_reads stay above barrier-2
        __builtin_amdgcn_s_barrier();          // reads done before buf reuse
    }

    #pragma unroll
    for (int i = 0; i < 4; ++i) {
        #pragma unroll
        for (int j = 0; j < 4; ++j) {
            int n = tileN + wc + j * 16 + l16;
            float bv = bias[n];
            #pragma unroll
            for (int r = 0; r < 4; ++r) {
                int m = tileM + wr + i * 16 + quad * 4 + r;
                float v = acc[i][j][r] + bv;
                if (EPI == 0) {
                    if (n < 768) {
                        outQ[(size_t)m * 768 + n] = f2bf(v);
                    } else if (n < 1536) {
                        outK[(size_t)m * 768 + (n - 768)] = f2bf(v * (0.125f * LOG2E));
                    } else {
                        outV[(size_t)m * 768 + (n - 1536)] = f2bf(v);
                    }
                } else {
                    outF[(size_t)m * N + n] = v;
                }
            }
        }
    }
}

// ---------------- MFMA flash attention, split-K (512-key chunks) ----------------
// grid 960 (1D), block 256 = 4 waves; EACH WAVE OWNS 32 Q-ROWS (2 groups of 16).
// LDS-BW optimization: K/V fragment reads are shared across both row groups
// (K-tile read 4x per block instead of 8x; same V), amask comes straight from
// global (L1-broadcast, off the LDS pipe). Per-block-tile LDS reads ~halved
// vs the 8-wave version; MFMA count identical. LDS 36.9KB -> 4 blocks/CU.
// XCD mapping (neutral r11): wgid&7 = XCD owns 3 heads x 40 chunks.
// Fixed-max softmax in base-2 domain (K pre-scaled 0.125*log2e).
__global__ __launch_bounds__(256) void attn_mfma_kernel(
    const u16* __restrict__ Q, const u16* __restrict__ Kg,
    const u16* __restrict__ Vtg, const float* __restrict__ amask,
    u16* __restrict__ Opart, float* __restrict__ Lpart) {
    __shared__ u16 Ks[64][72];
    __shared__ u16 Vt[64][72];          // V^T tile: [d][key]
    __shared__ u16 Ps[4][2][16][72];    // per-wave, per-group P [q][key]

    int wgid = blockIdx.x;
    int xcd = wgid & 7, local = wgid >> 3;      // local 0..119
    int bh = xcd * 3 + local / NCHUNK;          // 3 heads per XCD
    int px = local % NCHUNK;
    int b = bh / NHEAD, h = bh % NHEAD;
    int p = NCHUNK - 1 - px;                    // heavy chunks first per head
    int bx = 15, c = 0, a = 0;
    #pragma unroll
    for (int i = 0; i < 16; ++i) {
        int n = (i >> 2) + 1;               // chunks for q-tile i (512-key chunks)
        if (p < a + n) { bx = i; c = p - a; break; }
        a += n;
    }
    int kbase = c * 512;
    int nt = 2 * (bx + 1) - 8 * c;          // 64-key tiles in this chunk
    if (nt > 8) nt = 8;

    int t = threadIdx.x;
    int w = t >> 6, lane = t & 63;
    int quad = lane >> 4, l16 = lane & 15;
    size_t headbase = (size_t)b * (SEQ * NXC) + (size_t)h * (SEQ * HD);
    size_t headbaseT = (size_t)(b * NHEAD + h) * (SEQ * HD);

    int qw0 = bx * 128 + w * 32;            // wave owns 32 q-rows
    bf16x8 qf[2][2];
    #pragma unroll
    for (int g = 0; g < 2; ++g)
        #pragma unroll
        for (int s = 0; s < 2; ++s)
            qf[g][s] = *(const bf16x8*)&Q[headbase +
                (size_t)(qw0 + g * 16 + l16) * HD + s * 32 + quad * 8];

    float l_part[2] = {0.f, 0.f};           // per-lane partials (q-row l16, per group)
    f32x4 o[2][4] = {};

    // staging: 256 threads cover 64x64 K and V tiles, 2 slots per thread
    int r0a = t >> 3, c0a = (t & 7) * 8;    // slot a -> rows 0..31
    int r0b = r0a + 32;                     // slot b -> rows 32..63
    uint4 kra, krb, vra, vrb;
    {
        int k0 = kbase;
        kra = *(const uint4*)&Kg[headbase + (size_t)(k0 + r0a) * HD + c0a];
        krb = *(const uint4*)&Kg[headbase + (size_t)(k0 + r0b) * HD + c0a];
        vra = *(const uint4*)&Vtg[headbaseT + (size_t)r0a * SEQ + k0 + c0a];
        vrb = *(const uint4*)&Vtg[headbaseT + (size_t)r0b * SEQ + k0 + c0a];
    }

    for (int kt = 0; kt < nt; ++kt) {
        int k0 = kbase + kt * 64;
        __syncthreads();
        *(uint4*)&Ks[r0a][c0a] = kra;
        *(uint4*)&Ks[r0b][c0a] = krb;
        *(uint4*)&Vt[r0a][c0a] = vra;
        *(uint4*)&Vt[r0b][c0a] = vrb;
        __syncthreads();
        if (kt + 1 < nt) {
            int kn = k0 + 64;
            kra = *(const uint4*)&Kg[headbase + (size_t)(kn + r0a) * HD + c0a];
            krb = *(const uint4*)&Kg[headbase + (size_t)(kn + r0b) * HD + c0a];
            vra = *(const uint4*)&Vtg[headbaseT + (size_t)r0a * SEQ + kn + c0a];
            vrb = *(const uint4*)&Vtg[headbaseT + (size_t)r0b * SEQ + kn + c0a];
        }

        if (k0 > qw0 + 31) continue;        // tile fully past-causal for this wave
        bool g0act = (k0 <= qw0 + 15);      // group 0 has any in-causal keys

        // amask directly from global (16 lanes share each address -> L1 broadcast)
        f32x4 amv4[4];
        #pragma unroll
        for (int j = 0; j < 4; ++j)
            amv4[j] = *(const f32x4*)&amask[(size_t)b * SEQ + k0 + j * 16 + quad * 4];

        // S^T = K * Q^T for both row groups, kf reads SHARED across groups
        f32x4 sacc[2][4] = {};
        __builtin_amdgcn_s_setprio(1);
        #pragma unroll
        for (int s = 0; s < 2; ++s) {
            bf16x8 kf[4];
            #pragma unroll
            for (int j = 0; j < 4; ++j)
                kf[j] = *(const bf16x8*)&Ks[j * 16 + l16][s * 32 + quad * 8];
            #pragma unroll
            for (int j = 0; j < 4; ++j) {
                sacc[0][j] = __builtin_amdgcn_mfma_f32_16x16x32_bf16(kf[j], qf[0][s], sacc[0][j], 0, 0, 0);
                sacc[1][j] = __builtin_amdgcn_mfma_f32_16x16x32_bf16(kf[j], qf[1][s], sacc[1][j], 0, 0, 0);
            }
        }
        __builtin_amdgcn_s_setprio(0);

        #pragma unroll
        for (int g = 0; g < 2; ++g) {
            if (g == 0 && !g0act) continue;
            int qrow = qw0 + g * 16 + l16;
            bool diag = (k0 + 63 > qw0 + g * 16);
            #pragma unroll
            for (int j = 0; j < 4; ++j) {
                float pv[4];
                #pragma unroll
                for (int r = 0; r < 4; ++r) {
                    float pp = ex2(fmaf(amv4[j][r], LOG2E, sacc[g][j][r]));
                    if (diag && (k0 + j * 16 + quad * 4 + r > qrow)) pp = 0.f;
                    pv[r] = pp;
                }
                l_part[g] += (pv[0] + pv[1]) + (pv[2] + pv[3]);
                __hip_bfloat162 h01 = __float22bfloat162_rn(make_float2(pv[0], pv[1]));
                __hip_bfloat162 h23 = __float22bfloat162_rn(make_float2(pv[2], pv[3]));
                uint2 u;
                __builtin_memcpy(&u.x, &h01, 4);
                __builtin_memcpy(&u.y, &h23, 4);
                *(uint2*)&Ps[w][g][l16][j * 16 + quad * 4] = u;
            }
        }

        // PV: O[q][d] += P[q][k] * Vt[d][k]^T — vf reads SHARED across groups
        __builtin_amdgcn_s_setprio(1);
        #pragma unroll
        for (int s = 0; s < 2; ++s) {
            bf16x8 pf0 = {}, pf1;
            if (g0act) pf0 = *(const bf16x8*)&Ps[w][0][l16][s * 32 + quad * 8];
            pf1 = *(const bf16x8*)&Ps[w][1][l16][s * 32 + quad * 8];
            #pragma unroll
            for (int dc = 0; dc < 4; ++dc) {
                bf16x8 vf = *(const bf16x8*)&Vt[dc * 16 + l16][s * 32 + quad * 8];
                if (g0act)
                    o[0][dc] = __builtin_amdgcn_mfma_f32_16x16x32_bf16(pf0, vf, o[0][dc], 0, 0, 0);
                o[1][dc] = __builtin_amdgcn_mfma_f32_16x16x32_bf16(pf1, vf, o[1][dc], 0, 0, 0);
            }
        }
        __builtin_amdgcn_s_setprio(0);
    }

    // epilogue: reduce l across quads per group, write unnormalized partials
    u16* Ob = Opart + ((size_t)bh * NCHUNK + p) * (128 * 64);
    float* Lb = Lpart + ((size_t)bh * NCHUNK + p) * 128;
    #pragma unroll
    for (int g = 0; g < 2; ++g) {
        float l = l_part[g] + __shfl_xor(l_part[g], 16);
        l += __shfl_xor(l, 32);
        if (quad == 0) Lb[w * 32 + g * 16 + l16] = l;
        #pragma unroll
        for (int dc = 0; dc < 4; ++dc)
            #pragma unroll
            for (int r = 0; r < 4; ++r) {
                int rl = w * 32 + g * 16 + quad * 4 + r;
                Ob[rl * 64 + dc * 16 + l16] = f2bf(o[g][dc][r]);
            }
    }
}

// ---------------- combine partials -> bf16 A (vectorized, high-parallelism) ----
// grid (SEQ/32, BSZ*NHEAD), block 256: each block does 32 rows x 64 dims.
// 512-key chunk layout: ncs(bx) = (bx>>2)+1, p0 = (a+1)*(2a+b), a=bx>>2, b=bx&3.
__global__ __launch_bounds__(256) void attn_combine_kernel(
    const u16* __restrict__ Opart, const float* __restrict__ Lpart,
    u16* __restrict__ Aout) {
    __shared__ float winv[32];
    int bh = blockIdx.y;
    int b = bh / NHEAD, h = bh % NHEAD;
    int row0 = blockIdx.x * 32;             // global q-row base
    int bx = row0 >> 7;                     // 128-row q-tile
    int aa = bx >> 2, bb = bx & 3;
    int nch = aa + 1;                       // chunks for this tile (512-key)
    int p0 = (aa + 1) * (2 * aa + bb);
    int rbase = row0 & 127;                 // row offset within the 128-tile
    int t = threadIdx.x;

    if (t < 32) {
        float L = 0.f;
        for (int c = 0; c < nch; ++c)
            L += Lpart[((size_t)bh * NCHUNK + p0 + c) * 128 + rbase + t];
        winv[t] = 1.0f / L;
    }
    __syncthreads();

    int row = t >> 3;                       // 0..31
    int d0 = (t & 7) * 8;
    int rl = rbase + row;
    float acc[8] = {};
    for (int c = 0; c < nch; ++c) {
        uint4 u = *(const uint4*)&Opart[(((size_t)bh * NCHUNK + p0 + c) * 128 + rl) * 64 + d0];
        acc[0] += __uint_as_float(u.x << 16);
        acc[1] += __uint_as_float(u.x & 0xffff0000u);
        acc[2] += __uint_as_float(u.y << 16);
        acc[3] += __uint_as_float(u.y & 0xffff0000u);
        acc[4] += __uint_as_float(u.z << 16);
        acc[5] += __uint_as_float(u.z & 0xffff0000u);
        acc[6] += __uint_as_float(u.w << 16);
        acc[7] += __uint_as_float(u.w & 0xffff0000u);
    }
    float s = winv[row];
    uint4 o;
    o.x = pk2(acc[0] * s, acc[1] * s);
    o.y = pk2(acc[2] * s, acc[3] * s);
    o.z = pk2(acc[4] * s, acc[5] * s);
    o.w = pk2(acc[6] * s, acc[7] * s);
    *(uint4*)&Aout[((size_t)b * SEQ + row0 + row) * NXC + h * HD + d0] = o;
}

// ---------------- launcher ----------------
extern "C" void kernel_launch(void* const* d_in, const int* in_sizes, int n_in,
                              void* d_out, int out_size, void* d_ws, size_t ws_size,
                              hipStream_t stream) {
    const float* hs     = (const float*)d_in[0];
    const float* amask  = (const float*)d_in[1];
    const float* w_attn = (const float*)d_in[2];
    const float* b_attn = (const float*)d_in[3];
    const float* w_proj = (const float*)d_in[4];
    const float* b_proj = (const float*)d_in[5];
    float* out = (float*)d_out;

    const int M = BSZ * SEQ;            // 4096
    char* ws = (char*)d_ws;
    auto alloc = [&](size_t bytes) {
        char* p = ws;
        ws += (bytes + 255) & ~(size_t)255;
        return p;
    };
    u16* HSbf   = (u16*)alloc((size_t)M * NXC * 2);
    u16* WaT    = (u16*)alloc((size_t)3 * NXC * NXC * 2);   // 2304 x 768
    u16* WpT    = (u16*)alloc((size_t)NXC * NXC * 2);       // 768 x 768
    u16* Qb     = (u16*)alloc((size_t)M * NXC * 2);
    u16* Kb     = (u16*)alloc((size_t)M * NXC * 2);
    u16* Vb     = (u16*)alloc((size_t)M * NXC * 2);         // natural
    u16* Vtg    = (u16*)alloc((size_t)M * NXC * 2);         // per-head [d][s]
    u16* Ab     = (u16*)alloc((size_t)M * NXC * 2);
    u16* Opart  = (u16*)alloc((size_t)BSZ * NHEAD * NCHUNK * 128 * 64 * 2);
    float* Lpart = (float*)alloc((size_t)BSZ * NHEAD * NCHUNK * 128 * 4);

    // prep: cast HS + transpose both weights, one dispatch
    prep_kernel<<<dim3(5376), dim3(256), 0, stream>>>(hs, HSbf, w_attn, WaT, w_proj, WpT);
    // qkv gemm: M=4096, N=2304, K=768 -> bf16 Q/K/V natural (K pre-scaled)
    // 1D grid, XCD-swizzled in-kernel (18N x 32M = 576 blocks)
    gemm_bt_kernel<0><<<dim3((3 * NXC / 128) * (M / 128)), dim3(256), 0, stream>>>(
        HSbf, WaT, b_attn, Qb, Kb, Vb, nullptr, M, 3 * NXC, NXC);
    // per-head V transpose (direct-reshape semantics)
    vt_kernel<<<dim3(SEQ / 64, BSZ * NHEAD), dim3(256), 0, stream>>>(Vb, Vtg);
    // attention: split-K partials (512-key chunks), 4-wave/32-row blocks
    attn_mfma_kernel<<<dim3(NCHUNK * BSZ * NHEAD), dim3(256), 0, stream>>>(
        Qb, Kb, Vtg, amask, Opart, Lpart);
    attn_combine_kernel<<<dim3(SEQ / 32, BSZ * NHEAD), dim3(256), 0, stream>>>(
        Opart, Lpart, Ab);
    // proj gemm: M=4096, N=768, K=768 -> d_out fp32 (6N x 32M = 192 blocks)
    gemm_bt_kernel<1><<<dim3((NXC / 128) * (M / 128)), dim3(256), 0, stream>>>(
        Ab, WpT, b_proj, nullptr, nullptr, nullptr, out, M, NXC, NXC);
}

// Round 14
// 168.790 us; speedup vs baseline: 1.0337x; 1.0337x over previous
//
#include <hip/hip_runtime.h>
#include <hip/hip_bf16.h>

typedef unsigned short u16;
typedef short bf16x8 __attribute__((ext_vector_type(8)));
typedef float f32x4 __attribute__((ext_vector_type(4)));

#define NXC 768
#define NHEAD 12
#define SEQ 2048
#define BSZ 2
#define HD 64
#define NCHUNK 40   // sum over 16 q-tiles of ceil(128*(bx+1)/512)
#define LOG2E 1.4426950408889634f

__device__ inline u16 f2bf(float f) {
    unsigned int u = __float_as_uint(f);
    unsigned int r = u + 0x7fffu + ((u >> 16) & 1u);
    return (u16)(r >> 16);
}
__device__ inline unsigned pk2(float lo, float hi) {
    return (unsigned)f2bf(lo) | ((unsigned)f2bf(hi) << 16);
}
__device__ inline float ex2(float x) { return __builtin_amdgcn_exp2f(x); }

// async global->LDS, 16B per lane. LDS dest is wave-uniform base + lane*16.
__device__ inline void gld16(const u16* g, u16* l) {
    __builtin_amdgcn_global_load_lds(
        (const __attribute__((address_space(1))) unsigned int*)(g),
        (__attribute__((address_space(3))) unsigned int*)(l),
        16, 0, 0);
}

// ---------------- merged prep: cast HS + transpose-cast both weights --------
// grid 5376 x 256: blocks [0,3072) cast4, [3072,4800) w_attn^T, [4800,5376) w_proj^T
__global__ __launch_bounds__(256) void prep_kernel(
    const float* __restrict__ hs, u16* __restrict__ HSbf,
    const float* __restrict__ w_attn, u16* __restrict__ WaT,
    const float* __restrict__ w_proj, u16* __restrict__ WpT) {
    __shared__ float tile[32][33];
    int blk = blockIdx.x;
    int t = threadIdx.x;
    if (blk < 3072) {                       // cast: 786432 float4s
        int i = blk * 256 + t;
        float4 v = ((const float4*)hs)[i];
        ushort4 o;
        o.x = f2bf(v.x); o.y = f2bf(v.y); o.z = f2bf(v.z); o.w = f2bf(v.w);
        ((ushort4*)HSbf)[i] = o;
        return;
    }
    const float* in; u16* out; int C, cb, rb;
    if (blk < 4800) {                       // w_attn: 2304 cols x 768 rows
        int idx = blk - 3072;
        in = w_attn; out = WaT; C = 3 * NXC;
        cb = (idx % 72) * 32; rb = (idx / 72) * 32;
    } else {                                // w_proj: 768 x 768
        int idx = blk - 4800;
        in = w_proj; out = WpT; C = NXC;
        cb = (idx % 24) * 32; rb = (idx / 24) * 32;
    }
    int tx = t & 31, ty = t >> 5;           // (32,8) decomposition
    #pragma unroll
    for (int i = 0; i < 32; i += 8)
        tile[ty + i][tx] = in[(size_t)(rb + ty + i) * C + cb + tx];
    __syncthreads();
    #pragma unroll
    for (int i = 0; i < 32; i += 8)
        out[(size_t)(cb + ty + i) * NXC + rb + tx] = f2bf(tile[tx][ty + i]);
}

// per-head transpose: Vb head-chunk [ss][dd] -> Vtg [dd][ss] (both bf16).
// NOTE: interprets Vb's flat memory as [b*12+h][s][d] — matches the
// reference's DIRECT reshape semantics. Do not fuse into the GEMM epilogue.
__global__ __launch_bounds__(256) void vt_kernel(const u16* __restrict__ Vb,
                                                 u16* __restrict__ Vtg) {
    __shared__ u16 tile[64][68];
    int y = blockIdx.y;                        // b*NHEAD+h
    size_t base = (size_t)y * (SEQ * HD);
    int ss0 = blockIdx.x * 64;
    int t = threadIdx.x;
    #pragma unroll
    for (int c = t; c < 512; c += 256) {
        int r = c >> 3, col = (c & 7) * 8;
        *(uint4*)&tile[r][col] = *(const uint4*)&Vb[base + (size_t)(ss0 + r) * HD + col];
    }
    __syncthreads();
    #pragma unroll
    for (int c = t; c < 512; c += 256) {
        int dd = c >> 3, s8 = (c & 7) * 8;
        ushort4 a, bq;
        a.x = tile[s8 + 0][dd]; a.y = tile[s8 + 1][dd];
        a.z = tile[s8 + 2][dd]; a.w = tile[s8 + 3][dd];
        bq.x = tile[s8 + 4][dd]; bq.y = tile[s8 + 5][dd];
        bq.z = tile[s8 + 6][dd]; bq.w = tile[s8 + 7][dd];
        u16* dst = &Vtg[base + (size_t)dd * SEQ + ss0 + s8];
        *(ushort4*)dst = a;
        *(ushort4*)(dst + 4) = bq;
    }
}

// ---------------- GEMM: C[M][N] = A[M][K] * BT[N][K]^T + bias ----------------
// 128x128 tile, BK=32, 256 threads = 4 waves (2x2), each wave owns 64x64
// (4x4 16x16x32 frags, 16 MFMA per K-step). global_load_lds dwordx4 into a
// TRIPLE LDS buffer with prefetch depth 2 and counted s_waitcnt vmcnt(8).
// XCD-AWARE BLOCK SWIZZLE (T1, measured -2.9us r10): each XCD owns a
// contiguous (numN/2) x (numM/4) tile region so its operand panels
// (~3.3MB gemm0 / ~2.2MB gemm1) fit the 4MB per-XCD L2.
// EPI 0: bf16 Q, K (pre-scaled 0.125*log2e), V natural. EPI 1: fp32 out.
template <int EPI>
__global__ __launch_bounds__(256) void gemm_bt_kernel(
    const u16* __restrict__ A, const u16* __restrict__ BT,
    const float* __restrict__ bias,
    u16* __restrict__ outQ, u16* __restrict__ outK, u16* __restrict__ outV,
    float* __restrict__ outF,
    int M, int N, int K) {
    __shared__ u16 As[3 * 128 * 32];
    __shared__ u16 Bs[3 * 128 * 32];
    int numN = N >> 7, numM = M >> 7;
    int nPer = numN >> 1, mPer = numM >> 2;    // 2(N) x 4(M) XCD split
    int wgid = blockIdx.x;
    int xcd = wgid & 7, local = wgid >> 3;
    int nloc = local % nPer, mloc = local / nPer;
    int tileN = (((xcd & 1) * nPer) + nloc) << 7;
    int tileM = ((((xcd >> 1) & 3) * mPer) + mloc) << 7;
    int t = threadIdx.x;
    int lane = t & 63, wave = t >> 6;
    int wr = (wave >> 1) * 64, wc = (wave & 1) * 64;   // wave's 64x64 sub-tile
    int quad = lane >> 4, l16 = lane & 15;
    f32x4 acc[4][4] = {};

    int r0 = t >> 2, c0 = (t & 3) * 8;
    const u16* Ag0 = A + (size_t)(tileM + r0) * K + c0;
    const u16* Ag1 = Ag0 + (size_t)64 * K;
    const u16* Bg0 = BT + (size_t)(tileN + r0) * K + c0;
    const u16* Bg1 = Bg0 + (size_t)64 * K;
    u16* AsW0 = As + wave * 512;           // rows 0..63 half
    u16* AsW1 = As + 2048 + wave * 512;    // rows 64..127 half
    u16* BsW0 = Bs + wave * 512;
    u16* BsW1 = Bs + 2048 + wave * 512;

    // prologue: stage tiles 0 and 1 into buffers 0 and 1
    gld16(Ag0, AsW0);
    gld16(Ag1, AsW1);
    gld16(Bg0, BsW0);
    gld16(Bg1, BsW1);
    gld16(Ag0 + 32, AsW0 + 4096);
    gld16(Ag1 + 32, AsW1 + 4096);
    gld16(Bg0 + 32, BsW0 + 4096);
    gld16(Bg1 + 32, BsW1 + 4096);

    int NT = K >> 5;                       // 24 for K=768
    for (int tt = 0; tt < NT; ++tt) {
        int cur = tt % 3;
        if (tt + 2 < NT) {
            int kn = (tt + 2) * 32;
            int nb = ((tt + 2) % 3) * 4096;
            gld16(Ag0 + kn, AsW0 + nb);
            gld16(Ag1 + kn, AsW1 + nb);
            gld16(Bg0 + kn, BsW0 + nb);
            gld16(Bg1 + kn, BsW1 + nb);
            asm volatile("s_waitcnt vmcnt(8)" ::: "memory");  // tile tt landed
        } else if (tt + 1 < NT) {
            asm volatile("s_waitcnt vmcnt(4)" ::: "memory");  // tile tt landed
        } else {
            asm volatile("s_waitcnt vmcnt(0)" ::: "memory");
        }
        __builtin_amdgcn_s_barrier();          // all waves' tile-tt stage landed
        __builtin_amdgcn_sched_barrier(0);     // nothing moves above the barrier

        const u16* Ac = As + cur * 4096;
        const u16* Bc = Bs + cur * 4096;
        bf16x8 af[4], bfr[4];
        #pragma unroll
        for (int i = 0; i < 4; ++i)
            af[i] = *(const bf16x8*)&Ac[(wr + i * 16 + l16) * 32 + quad * 8];
        #pragma unroll
        for (int j = 0; j < 4; ++j)
            bfr[j] = *(const bf16x8*)&Bc[(wc + j * 16 + l16) * 32 + quad * 8];
        #pragma unroll
        for (int i = 0; i < 4; ++i)
            #pragma unroll
            for (int j = 0; j < 4; ++j)
                acc[i][j] = __builtin_amdgcn_mfma_f32_16x16x32_bf16(af[i], bfr[j], acc[i][j], 0, 0, 0);

        __builtin_amdgcn_sched_barrier(0);     // ds_reads stay above barrier-2
        __builtin_amdgcn_s_barrier();          // reads done before buf reuse
    }

    #pragma unroll
    for (int i = 0; i < 4; ++i) {
        #pragma unroll
        for (int j = 0; j < 4; ++j) {
            int n = tileN + wc + j * 16 + l16;
            float bv = bias[n];
            #pragma unroll
            for (int r = 0; r < 4; ++r) {
                int m = tileM + wr + i * 16 + quad * 4 + r;
                float v = acc[i][j][r] + bv;
                if (EPI == 0) {
                    if (n < 768) {
                        outQ[(size_t)m * 768 + n] = f2bf(v);
                    } else if (n < 1536) {
                        outK[(size_t)m * 768 + (n - 768)] = f2bf(v * (0.125f * LOG2E));
                    } else {
                        outV[(size_t)m * 768 + (n - 1536)] = f2bf(v);
                    }
                } else {
                    outF[(size_t)m * N + n] = v;
                }
            }
        }
    }
}

// ---------------- MFMA flash attention, split-K (512-key chunks) ----------------
// grid (NCHUNK, BSZ*NHEAD), block 512: 8 waves x 16 q-rows (best-measured r10
// structure). Fixed-max softmax in base-2 domain (K pre-scaled 0.125*log2e).
// VALU cut vs r10: the causal-mask compare+cndmask runs ONLY in the
// wave-uniform diagonal branch (one tile per wave); fully-causal tiles take
// the maskless path — bit-identical output (mask was always-false there),
// ~2 of 5 VALU ops per element removed on ~3/4 of tiles.
__global__ __launch_bounds__(512) void attn_mfma_kernel(
    const u16* __restrict__ Q, const u16* __restrict__ Kg,
    const u16* __restrict__ Vtg, const float* __restrict__ amask,
    u16* __restrict__ Opart, float* __restrict__ Lpart) {
    __shared__ u16 Ks[64][72];
    __shared__ u16 Vt[64][72];          // V^T tile: [d][key]
    __shared__ u16 Ps[8][16][72];       // per-wave P [q][key]
    __shared__ float Ams[64];

    int bh = blockIdx.y;
    int b = bh / NHEAD, h = bh % NHEAD;
    int p = NCHUNK - 1 - (int)blockIdx.x;   // heavy chunks dispatch first
    int bx = 15, c = 0, a = 0;
    #pragma unroll
    for (int i = 0; i < 16; ++i) {
        int n = (i >> 2) + 1;               // chunks for q-tile i (512-key chunks)
        if (p < a + n) { bx = i; c = p - a; break; }
        a += n;
    }
    int kbase = c * 512;
    int nt = 2 * (bx + 1) - 8 * c;          // 64-key tiles in this chunk
    if (nt > 8) nt = 8;

    int t = threadIdx.x;
    int w = t >> 6, lane = t & 63;
    int quad = lane >> 4, l16 = lane & 15;
    size_t headbase = (size_t)b * (SEQ * NXC) + (size_t)h * (SEQ * HD);
    size_t headbaseT = (size_t)(b * NHEAD + h) * (SEQ * HD);

    int r0 = bx * 128;
    int qw0 = r0 + w * 16;                  // wave owns 16 q-rows
    int qrow = qw0 + l16;
    bf16x8 qf[2];
    #pragma unroll
    for (int s = 0; s < 2; ++s)
        qf[s] = *(const bf16x8*)&Q[headbase + (size_t)(qw0 + l16) * HD + s * 32 + quad * 8];

    float l_part = 0.f;                     // per-lane partial of l
    f32x4 o[4] = {};

    // register prefetch of tile 0 (512 threads cover 64x64 K and V^T tiles)
    int pr_row = t >> 3, pr_col = (t & 7) * 8;
    uint4 kr, vr; float amr;
    {
        int k0 = kbase;
        kr = *(const uint4*)&Kg[headbase + (size_t)(k0 + pr_row) * HD + pr_col];
        vr = *(const uint4*)&Vtg[headbaseT + (size_t)pr_row * SEQ + k0 + pr_col];
        if (t < 64) amr = amask[(size_t)b * SEQ + k0 + t];
    }

    for (int kt = 0; kt < nt; ++kt) {
        int k0 = kbase + kt * 64;
        __syncthreads();
        *(uint4*)&Ks[pr_row][pr_col] = kr;
        *(uint4*)&Vt[pr_row][pr_col] = vr;
        if (t < 64) Ams[t] = amr * LOG2E;
        __syncthreads();
        if (kt + 1 < nt) {
            int kn = k0 + 64;
            kr = *(const uint4*)&Kg[headbase + (size_t)(kn + pr_row) * HD + pr_col];
            vr = *(const uint4*)&Vtg[headbaseT + (size_t)pr_row * SEQ + kn + pr_col];
            if (t < 64) amr = amask[(size_t)b * SEQ + kn + t];
        }

        if (k0 > qw0 + 15) continue;        // tile fully past-causal for this wave

        bf16x8 kf[2][4];
        #pragma unroll
        for (int s = 0; s < 2; ++s)
            #pragma unroll
            for (int j = 0; j < 4; ++j)
                kf[s][j] = *(const bf16x8*)&Ks[j * 16 + l16][s * 32 + quad * 8];
        f32x4 amv4[4];
        #pragma unroll
        for (int j = 0; j < 4; ++j)
            amv4[j] = *(const f32x4*)&Ams[j * 16 + quad * 4];

        // S^T = K * Q^T : lane owns q-row = l16
        f32x4 sacc[4] = {};
        __builtin_amdgcn_s_setprio(1);
        #pragma unroll
        for (int s = 0; s < 2; ++s)
            #pragma unroll
            for (int j = 0; j < 4; ++j)
                sacc[j] = __builtin_amdgcn_mfma_f32_16x16x32_bf16(kf[s][j], qf[s], sacc[j], 0, 0, 0);
        __builtin_amdgcn_s_setprio(0);

        if (k0 + 63 > qw0) {
            // diagonal tile (wave-uniform branch): per-element causal mask
            #pragma unroll
            for (int j = 0; j < 4; ++j) {
                float pv[4];
                #pragma unroll
                for (int r = 0; r < 4; ++r) {
                    float pp = ex2(sacc[j][r] + amv4[j][r]);
                    if (k0 + j * 16 + quad * 4 + r > qrow) pp = 0.f;
                    pv[r] = pp;
                }
                l_part += (pv[0] + pv[1]) + (pv[2] + pv[3]);
                __hip_bfloat162 h01 = __float22bfloat162_rn(make_float2(pv[0], pv[1]));
                __hip_bfloat162 h23 = __float22bfloat162_rn(make_float2(pv[2], pv[3]));
                uint2 u;
                __builtin_memcpy(&u.x, &h01, 4);
                __builtin_memcpy(&u.y, &h23, 4);
                *(uint2*)&Ps[w][l16][j * 16 + quad * 4] = u;
            }
        } else {
            // fully-causal tile: maskless (bit-identical — mask was never hit)
            #pragma unroll
            for (int j = 0; j < 4; ++j) {
                float pv[4];
                #pragma unroll
                for (int r = 0; r < 4; ++r)
                    pv[r] = ex2(sacc[j][r] + amv4[j][r]);
                l_part += (pv[0] + pv[1]) + (pv[2] + pv[3]);
                __hip_bfloat162 h01 = __float22bfloat162_rn(make_float2(pv[0], pv[1]));
                __hip_bfloat162 h23 = __float22bfloat162_rn(make_float2(pv[2], pv[3]));
                uint2 u;
                __builtin_memcpy(&u.x, &h01, 4);
                __builtin_memcpy(&u.y, &h23, 4);
                *(uint2*)&Ps[w][l16][j * 16 + quad * 4] = u;
            }
        }

        // PV: O[q][d] += P[q][k] * Vt[d][k]^T   (no rescale — fixed m)
        __builtin_amdgcn_s_setprio(1);
        #pragma unroll
        for (int s = 0; s < 2; ++s) {
            bf16x8 pf = *(const bf16x8*)&Ps[w][l16][s * 32 + quad * 8];
            #pragma unroll
            for (int dc = 0; dc < 4; ++dc) {
                bf16x8 vf = *(const bf16x8*)&Vt[dc * 16 + l16][s * 32 + quad * 8];
                o[dc] = __builtin_amdgcn_mfma_f32_16x16x32_bf16(pf, vf, o[dc], 0, 0, 0);
            }
        }
        __builtin_amdgcn_s_setprio(0);
    }

    // epilogue: reduce l across quads once, write unnormalized partials
    float l = l_part + __shfl_xor(l_part, 16);
    l += __shfl_xor(l, 32);
    u16* Ob = Opart + ((size_t)bh * NCHUNK + p) * (128 * 64);
    float* Lb = Lpart + ((size_t)bh * NCHUNK + p) * 128;
    #pragma unroll
    for (int dc = 0; dc < 4; ++dc)
        #pragma unroll
        for (int r = 0; r < 4; ++r) {
            int rl = w * 16 + quad * 4 + r;
            Ob[rl * 64 + dc * 16 + l16] = f2bf(o[dc][r]);
        }
    if (quad == 0) Lb[w * 16 + l16] = l;
}

// ---------------- combine partials -> bf16 A (vectorized, high-parallelism) ----
// grid (SEQ/32, BSZ*NHEAD), block 256: each block does 32 rows x 64 dims.
// 512-key chunk layout: ncs(bx) = (bx>>2)+1, p0 = (a+1)*(2a+b), a=bx>>2, b=bx&3.
__global__ __launch_bounds__(256) void attn_combine_kernel(
    const u16* __restrict__ Opart, const float* __restrict__ Lpart,
    u16* __restrict__ Aout) {
    __shared__ float winv[32];
    int bh = blockIdx.y;
    int b = bh / NHEAD, h = bh % NHEAD;
    int row0 = blockIdx.x * 32;             // global q-row base
    int bx = row0 >> 7;                     // 128-row q-tile
    int aa = bx >> 2, bb = bx & 3;
    int nch = aa + 1;                       // chunks for this tile (512-key)
    int p0 = (aa + 1) * (2 * aa + bb);
    int rbase = row0 & 127;                 // row offset within the 128-tile
    int t = threadIdx.x;

    if (t < 32) {
        float L = 0.f;
        for (int c = 0; c < nch; ++c)
            L += Lpart[((size_t)bh * NCHUNK + p0 + c) * 128 + rbase + t];
        winv[t] = 1.0f / L;
    }
    __syncthreads();

    int row = t >> 3;                       // 0..31
    int d0 = (t & 7) * 8;
    int rl = rbase + row;
    float acc[8] = {};
    for (int c = 0; c < nch; ++c) {
        uint4 u = *(const uint4*)&Opart[(((size_t)bh * NCHUNK + p0 + c) * 128 + rl) * 64 + d0];
        acc[0] += __uint_as_float(u.x << 16);
        acc[1] += __uint_as_float(u.x & 0xffff0000u);
        acc[2] += __uint_as_float(u.y << 16);
        acc[3] += __uint_as_float(u.y & 0xffff0000u);
        acc[4] += __uint_as_float(u.z << 16);
        acc[5] += __uint_as_float(u.z & 0xffff0000u);
        acc[6] += __uint_as_float(u.w << 16);
        acc[7] += __uint_as_float(u.w & 0xffff0000u);
    }
    float s = winv[row];
    uint4 o;
    o.x = pk2(acc[0] * s, acc[1] * s);
    o.y = pk2(acc[2] * s, acc[3] * s);
    o.z = pk2(acc[4] * s, acc[5] * s);
    o.w = pk2(acc[6] * s, acc[7] * s);
    *(uint4*)&Aout[((size_t)b * SEQ + row0 + row) * NXC + h * HD + d0] = o;
}

// ---------------- launcher ----------------
extern "C" void kernel_launch(void* const* d_in, const int* in_sizes, int n_in,
                              void* d_out, int out_size, void* d_ws, size_t ws_size,
                              hipStream_t stream) {
    const float* hs     = (const float*)d_in[0];
    const float* amask  = (const float*)d_in[1];
    const float* w_attn = (const float*)d_in[2];
    const float* b_attn = (const float*)d_in[3];
    const float* w_proj = (const float*)d_in[4];
    const float* b_proj = (const float*)d_in[5];
    float* out = (float*)d_out;

    const int M = BSZ * SEQ;            // 4096
    char* ws = (char*)d_ws;
    auto alloc = [&](size_t bytes) {
        char* p = ws;
        ws += (bytes + 255) & ~(size_t)255;
        return p;
    };
    u16* HSbf   = (u16*)alloc((size_t)M * NXC * 2);
    u16* WaT    = (u16*)alloc((size_t)3 * NXC * NXC * 2);   // 2304 x 768
    u16* WpT    = (u16*)alloc((size_t)NXC * NXC * 2);       // 768 x 768
    u16* Qb     = (u16*)alloc((size_t)M * NXC * 2);
    u16* Kb     = (u16*)alloc((size_t)M * NXC * 2);
    u16* Vb     = (u16*)alloc((size_t)M * NXC * 2);         // natural
    u16* Vtg    = (u16*)alloc((size_t)M * NXC * 2);         // per-head [d][s]
    u16* Ab     = (u16*)alloc((size_t)M * NXC * 2);
    u16* Opart  = (u16*)alloc((size_t)BSZ * NHEAD * NCHUNK * 128 * 64 * 2);
    float* Lpart = (float*)alloc((size_t)BSZ * NHEAD * NCHUNK * 128 * 4);

    // prep: cast HS + transpose both weights, one dispatch
    prep_kernel<<<dim3(5376), dim3(256), 0, stream>>>(hs, HSbf, w_attn, WaT, w_proj, WpT);
    // qkv gemm: M=4096, N=2304, K=768 -> bf16 Q/K/V natural (K pre-scaled)
    // 1D grid, XCD-swizzled in-kernel (18N x 32M = 576 blocks)
    gemm_bt_kernel<0><<<dim3((3 * NXC / 128) * (M / 128)), dim3(256), 0, stream>>>(
        HSbf, WaT, b_attn, Qb, Kb, Vb, nullptr, M, 3 * NXC, NXC);
    // per-head V transpose (direct-reshape semantics)
    vt_kernel<<<dim3(SEQ / 64, BSZ * NHEAD), dim3(256), 0, stream>>>(Vb, Vtg);
    // attention: split-K partials (512-key chunks), then combine
    attn_mfma_kernel<<<dim3(NCHUNK, BSZ * NHEAD), dim3(512), 0, stream>>>(
        Qb, Kb, Vtg, amask, Opart, Lpart);
    attn_combine_kernel<<<dim3(SEQ / 32, BSZ * NHEAD), dim3(256), 0, stream>>>(
        Opart, Lpart, Ab);
    // proj gemm: M=4096, N=768, K=768 -> d_out fp32 (6N x 32M = 192 blocks)
    gemm_bt_kernel<1><<<dim3((NXC / 128) * (M / 128)), dim3(256), 0, stream>>>(
        Ab, WpT, b_proj, nullptr, nullptr, nullptr, out, M, NXC, NXC);
}

// Round 15
// 167.806 us; speedup vs baseline: 1.0397x; 1.0059x over previous
//
#include <hip/hip_runtime.h>
#include <hip/hip_bf16.h>

typedef unsigned short u16;
typedef short bf16x8 __attribute__((ext_vector_type(8)));
typedef float f32x4 __attribute__((ext_vector_type(4)));

#define NXC 768
#define NHEAD 12
#define SEQ 2048
#define BSZ 2
#define HD 64
#define NCHUNK 40   // sum over 16 q-tiles of ceil(128*(bx+1)/512)
#define LOG2E 1.4426950408889634f

__device__ inline u16 f2bf(float f) {
    unsigned int u = __float_as_uint(f);
    unsigned int r = u + 0x7fffu + ((u >> 16) & 1u);
    return (u16)(r >> 16);
}
__device__ inline unsigned pk2(float lo, float hi) {
    return (unsigned)f2bf(lo) | ((unsigned)f2bf(hi) << 16);
}
__device__ inline float ex2(float x) { return __builtin_amdgcn_exp2f(x); }

// async global->LDS, 16B per lane. LDS dest is wave-uniform base + lane*16.
__device__ inline void gld16(const u16* g, u16* l) {
    __builtin_amdgcn_global_load_lds(
        (const __attribute__((address_space(1))) unsigned int*)(g),
        (__attribute__((address_space(3))) unsigned int*)(l),
        16, 0, 0);
}

// ---------------- merged prep: cast HS + transpose-cast both weights --------
// grid 5376 x 256: blocks [0,3072) cast4, [3072,4800) w_attn^T, [4800,5376) w_proj^T
__global__ __launch_bounds__(256) void prep_kernel(
    const float* __restrict__ hs, u16* __restrict__ HSbf,
    const float* __restrict__ w_attn, u16* __restrict__ WaT,
    const float* __restrict__ w_proj, u16* __restrict__ WpT) {
    __shared__ float tile[32][33];
    int blk = blockIdx.x;
    int t = threadIdx.x;
    if (blk < 3072) {                       // cast: 786432 float4s
        int i = blk * 256 + t;
        float4 v = ((const float4*)hs)[i];
        ushort4 o;
        o.x = f2bf(v.x); o.y = f2bf(v.y); o.z = f2bf(v.z); o.w = f2bf(v.w);
        ((ushort4*)HSbf)[i] = o;
        return;
    }
    const float* in; u16* out; int C, cb, rb;
    if (blk < 4800) {                       // w_attn: 2304 cols x 768 rows
        int idx = blk - 3072;
        in = w_attn; out = WaT; C = 3 * NXC;
        cb = (idx % 72) * 32; rb = (idx / 72) * 32;
    } else {                                // w_proj: 768 x 768
        int idx = blk - 4800;
        in = w_proj; out = WpT; C = NXC;
        cb = (idx % 24) * 32; rb = (idx / 24) * 32;
    }
    int tx = t & 31, ty = t >> 5;           // (32,8) decomposition
    #pragma unroll
    for (int i = 0; i < 32; i += 8)
        tile[ty + i][tx] = in[(size_t)(rb + ty + i) * C + cb + tx];
    __syncthreads();
    #pragma unroll
    for (int i = 0; i < 32; i += 8)
        out[(size_t)(cb + ty + i) * NXC + rb + tx] = f2bf(tile[tx][ty + i]);
}

// per-head transpose: Vb head-chunk [ss][dd] -> Vtg [dd][ss] (both bf16).
// NOTE: interprets Vb's flat memory as [b*12+h][s][d] — matches the
// reference's DIRECT reshape semantics. Do not fuse into the GEMM epilogue.
__global__ __launch_bounds__(256) void vt_kernel(const u16* __restrict__ Vb,
                                                 u16* __restrict__ Vtg) {
    __shared__ u16 tile[64][68];
    int y = blockIdx.y;                        // b*NHEAD+h
    size_t base = (size_t)y * (SEQ * HD);
    int ss0 = blockIdx.x * 64;
    int t = threadIdx.x;
    #pragma unroll
    for (int c = t; c < 512; c += 256) {
        int r = c >> 3, col = (c & 7) * 8;
        *(uint4*)&tile[r][col] = *(const uint4*)&Vb[base + (size_t)(ss0 + r) * HD + col];
    }
    __syncthreads();
    #pragma unroll
    for (int c = t; c < 512; c += 256) {
        int dd = c >> 3, s8 = (c & 7) * 8;
        ushort4 a, bq;
        a.x = tile[s8 + 0][dd]; a.y = tile[s8 + 1][dd];
        a.z = tile[s8 + 2][dd]; a.w = tile[s8 + 3][dd];
        bq.x = tile[s8 + 4][dd]; bq.y = tile[s8 + 5][dd];
        bq.z = tile[s8 + 6][dd]; bq.w = tile[s8 + 7][dd];
        u16* dst = &Vtg[base + (size_t)dd * SEQ + ss0 + s8];
        *(ushort4*)dst = a;
        *(ushort4*)(dst + 4) = bq;
    }
}

// ---------------- GEMM: C[M][N] = A[M][K] * BT[N][K]^T + bias ----------------
// 128x128 tile, BK=32, 256 threads = 4 waves (2x2), each wave owns 64x64
// (4x4 16x16x32 frags, 16 MFMA per K-step). global_load_lds dwordx4 into a
// TRIPLE LDS buffer with prefetch depth 2 and counted s_waitcnt vmcnt(8).
// XCD-AWARE BLOCK SWIZZLE (T1, measured -2.9us r10): each XCD owns a
// contiguous (numN/2) x (numM/4) tile region so its operand panels
// (~3.3MB gemm0 / ~2.2MB gemm1) fit the 4MB per-XCD L2.
// EPI 0: bf16 Q, K (pre-scaled 0.125*log2e), V natural. EPI 1: fp32 out.
template <int EPI>
__global__ __launch_bounds__(256) void gemm_bt_kernel(
    const u16* __restrict__ A, const u16* __restrict__ BT,
    const float* __restrict__ bias,
    u16* __restrict__ outQ, u16* __restrict__ outK, u16* __restrict__ outV,
    float* __restrict__ outF,
    int M, int N, int K) {
    __shared__ u16 As[3 * 128 * 32];
    __shared__ u16 Bs[3 * 128 * 32];
    int numN = N >> 7, numM = M >> 7;
    int nPer = numN >> 1, mPer = numM >> 2;    // 2(N) x 4(M) XCD split
    int wgid = blockIdx.x;
    int xcd = wgid & 7, local = wgid >> 3;
    int nloc = local % nPer, mloc = local / nPer;
    int tileN = (((xcd & 1) * nPer) + nloc) << 7;
    int tileM = ((((xcd >> 1) & 3) * mPer) + mloc) << 7;
    int t = threadIdx.x;
    int lane = t & 63, wave = t >> 6;
    int wr = (wave >> 1) * 64, wc = (wave & 1) * 64;   // wave's 64x64 sub-tile
    int quad = lane >> 4, l16 = lane & 15;
    f32x4 acc[4][4] = {};

    int r0 = t >> 2, c0 = (t & 3) * 8;
    const u16* Ag0 = A + (size_t)(tileM + r0) * K + c0;
    const u16* Ag1 = Ag0 + (size_t)64 * K;
    const u16* Bg0 = BT + (size_t)(tileN + r0) * K + c0;
    const u16* Bg1 = Bg0 + (size_t)64 * K;
    u16* AsW0 = As + wave * 512;           // rows 0..63 half
    u16* AsW1 = As + 2048 + wave * 512;    // rows 64..127 half
    u16* BsW0 = Bs + wave * 512;
    u16* BsW1 = Bs + 2048 + wave * 512;

    // prologue: stage tiles 0 and 1 into buffers 0 and 1
    gld16(Ag0, AsW0);
    gld16(Ag1, AsW1);
    gld16(Bg0, BsW0);
    gld16(Bg1, BsW1);
    gld16(Ag0 + 32, AsW0 + 4096);
    gld16(Ag1 + 32, AsW1 + 4096);
    gld16(Bg0 + 32, BsW0 + 4096);
    gld16(Bg1 + 32, BsW1 + 4096);

    int NT = K >> 5;                       // 24 for K=768
    for (int tt = 0; tt < NT; ++tt) {
        int cur = tt % 3;
        if (tt + 2 < NT) {
            int kn = (tt + 2) * 32;
            int nb = ((tt + 2) % 3) * 4096;
            gld16(Ag0 + kn, AsW0 + nb);
            gld16(Ag1 + kn, AsW1 + nb);
            gld16(Bg0 + kn, BsW0 + nb);
            gld16(Bg1 + kn, BsW1 + nb);
            asm volatile("s_waitcnt vmcnt(8)" ::: "memory");  // tile tt landed
        } else if (tt + 1 < NT) {
            asm volatile("s_waitcnt vmcnt(4)" ::: "memory");  // tile tt landed
        } else {
            asm volatile("s_waitcnt vmcnt(0)" ::: "memory");
        }
        __builtin_amdgcn_s_barrier();          // all waves' tile-tt stage landed
        __builtin_amdgcn_sched_barrier(0);     // nothing moves above the barrier

        const u16* Ac = As + cur * 4096;
        const u16* Bc = Bs + cur * 4096;
        bf16x8 af[4], bfr[4];
        #pragma unroll
        for (int i = 0; i < 4; ++i)
            af[i] = *(const bf16x8*)&Ac[(wr + i * 16 + l16) * 32 + quad * 8];
        #pragma unroll
        for (int j = 0; j < 4; ++j)
            bfr[j] = *(const bf16x8*)&Bc[(wc + j * 16 + l16) * 32 + quad * 8];
        #pragma unroll
        for (int i = 0; i < 4; ++i)
            #pragma unroll
            for (int j = 0; j < 4; ++j)
                acc[i][j] = __builtin_amdgcn_mfma_f32_16x16x32_bf16(af[i], bfr[j], acc[i][j], 0, 0, 0);

        __builtin_amdgcn_sched_barrier(0);     // ds_reads stay above barrier-2
        __builtin_amdgcn_s_barrier();          // reads done before buf reuse
    }

    #pragma unroll
    for (int i = 0; i < 4; ++i) {
        #pragma unroll
        for (int j = 0; j < 4; ++j) {
            int n = tileN + wc + j * 16 + l16;
            float bv = bias[n];
            #pragma unroll
            for (int r = 0; r < 4; ++r) {
                int m = tileM + wr + i * 16 + quad * 4 + r;
                float v = acc[i][j][r] + bv;
                if (EPI == 0) {
                    if (n < 768) {
                        outQ[(size_t)m * 768 + n] = f2bf(v);
                    } else if (n < 1536) {
                        outK[(size_t)m * 768 + (n - 768)] = f2bf(v * (0.125f * LOG2E));
                    } else {
                        outV[(size_t)m * 768 + (n - 1536)] = f2bf(v);
                    }
                } else {
                    outF[(size_t)m * N + n] = v;
                }
            }
        }
    }
}

// ---------------- MFMA flash attention, split-K (512-key chunks) ----------------
// grid (NCHUNK, BSZ*NHEAD), block 512: 8 waves x 16 q-rows. Fixed-max softmax
// in base-2 domain (K pre-scaled 0.125*log2e). Wave-uniform diag split (r14,
// -3us). NEW (r15): the softmax denominator l[q] = sum_k P[q][k] is computed
// on the MFMA pipe via a ones-vector B-operand — 2 extra MFMA/tile replace
// 12 VALU adds/lane-tile + the epilogue cross-lane shuffles (attn is
// VALU-bound: r13 counters VALUBusy 37% vs MfmaUtil 11%). l now sums the
// bf16-quantized P (same values PV consumes); |delta l| <= 0.2% -> well
// inside threshold.
__global__ __launch_bounds__(512) void attn_mfma_kernel(
    const u16* __restrict__ Q, const u16* __restrict__ Kg,
    const u16* __restrict__ Vtg, const float* __restrict__ amask,
    u16* __restrict__ Opart, float* __restrict__ Lpart) {
    __shared__ u16 Ks[64][72];
    __shared__ u16 Vt[64][72];          // V^T tile: [d][key]
    __shared__ u16 Ps[8][16][72];       // per-wave P [q][key]
    __shared__ float Ams[64];

    int bh = blockIdx.y;
    int b = bh / NHEAD, h = bh % NHEAD;
    int p = NCHUNK - 1 - (int)blockIdx.x;   // heavy chunks dispatch first
    int bx = 15, c = 0, a = 0;
    #pragma unroll
    for (int i = 0; i < 16; ++i) {
        int n = (i >> 2) + 1;               // chunks for q-tile i (512-key chunks)
        if (p < a + n) { bx = i; c = p - a; break; }
        a += n;
    }
    int kbase = c * 512;
    int nt = 2 * (bx + 1) - 8 * c;          // 64-key tiles in this chunk
    if (nt > 8) nt = 8;

    int t = threadIdx.x;
    int w = t >> 6, lane = t & 63;
    int quad = lane >> 4, l16 = lane & 15;
    size_t headbase = (size_t)b * (SEQ * NXC) + (size_t)h * (SEQ * HD);
    size_t headbaseT = (size_t)(b * NHEAD + h) * (SEQ * HD);

    int r0 = bx * 128;
    int qw0 = r0 + w * 16;                  // wave owns 16 q-rows
    int qrow = qw0 + l16;
    bf16x8 qf[2];
    #pragma unroll
    for (int s = 0; s < 2; ++s)
        qf[s] = *(const bf16x8*)&Q[headbase + (size_t)(qw0 + l16) * HD + s * 32 + quad * 8];

    // ones B-operand for the row-sum MFMA (bf16 1.0 = 0x3F80)
    bf16x8 vones;
    #pragma unroll
    for (int i = 0; i < 8; ++i) vones[i] = (short)0x3F80;

    f32x4 lacc = {};                        // l for q-rows quad*4+r (all l16 cols equal)
    f32x4 o[4] = {};

    // register prefetch of tile 0 (512 threads cover 64x64 K and V^T tiles)
    int pr_row = t >> 3, pr_col = (t & 7) * 8;
    uint4 kr, vr; float amr;
    {
        int k0 = kbase;
        kr = *(const uint4*)&Kg[headbase + (size_t)(k0 + pr_row) * HD + pr_col];
        vr = *(const uint4*)&Vtg[headbaseT + (size_t)pr_row * SEQ + k0 + pr_col];
        if (t < 64) amr = amask[(size_t)b * SEQ + k0 + t];
    }

    for (int kt = 0; kt < nt; ++kt) {
        int k0 = kbase + kt * 64;
        __syncthreads();
        *(uint4*)&Ks[pr_row][pr_col] = kr;
        *(uint4*)&Vt[pr_row][pr_col] = vr;
        if (t < 64) Ams[t] = amr * LOG2E;
        __syncthreads();
        if (kt + 1 < nt) {
            int kn = k0 + 64;
            kr = *(const uint4*)&Kg[headbase + (size_t)(kn + pr_row) * HD + pr_col];
            vr = *(const uint4*)&Vtg[headbaseT + (size_t)pr_row * SEQ + kn + pr_col];
            if (t < 64) amr = amask[(size_t)b * SEQ + kn + t];
        }

        if (k0 > qw0 + 15) continue;        // tile fully past-causal for this wave

        bf16x8 kf[2][4];
        #pragma unroll
        for (int s = 0; s < 2; ++s)
            #pragma unroll
            for (int j = 0; j < 4; ++j)
                kf[s][j] = *(const bf16x8*)&Ks[j * 16 + l16][s * 32 + quad * 8];
        f32x4 amv4[4];
        #pragma unroll
        for (int j = 0; j < 4; ++j)
            amv4[j] = *(const f32x4*)&Ams[j * 16 + quad * 4];

        // S^T = K * Q^T : lane owns q-row = l16
        f32x4 sacc[4] = {};
        __builtin_amdgcn_s_setprio(1);
        #pragma unroll
        for (int s = 0; s < 2; ++s)
            #pragma unroll
            for (int j = 0; j < 4; ++j)
                sacc[j] = __builtin_amdgcn_mfma_f32_16x16x32_bf16(kf[s][j], qf[s], sacc[j], 0, 0, 0);
        __builtin_amdgcn_s_setprio(0);

        if (k0 + 63 > qw0) {
            // diagonal tile (wave-uniform branch): per-element causal mask
            #pragma unroll
            for (int j = 0; j < 4; ++j) {
                float pv[4];
                #pragma unroll
                for (int r = 0; r < 4; ++r) {
                    float pp = ex2(sacc[j][r] + amv4[j][r]);
                    if (k0 + j * 16 + quad * 4 + r > qrow) pp = 0.f;
                    pv[r] = pp;
                }
                __hip_bfloat162 h01 = __float22bfloat162_rn(make_float2(pv[0], pv[1]));
                __hip_bfloat162 h23 = __float22bfloat162_rn(make_float2(pv[2], pv[3]));
                uint2 u;
                __builtin_memcpy(&u.x, &h01, 4);
                __builtin_memcpy(&u.y, &h23, 4);
                *(uint2*)&Ps[w][l16][j * 16 + quad * 4] = u;
            }
        } else {
            // fully-causal tile: maskless (bit-identical — mask was never hit)
            #pragma unroll
            for (int j = 0; j < 4; ++j) {
                float pv[4];
                #pragma unroll
                for (int r = 0; r < 4; ++r)
                    pv[r] = ex2(sacc[j][r] + amv4[j][r]);
                __hip_bfloat162 h01 = __float22bfloat162_rn(make_float2(pv[0], pv[1]));
                __hip_bfloat162 h23 = __float22bfloat162_rn(make_float2(pv[2], pv[3]));
                uint2 u;
                __builtin_memcpy(&u.x, &h01, 4);
                __builtin_memcpy(&u.y, &h23, 4);
                *(uint2*)&Ps[w][l16][j * 16 + quad * 4] = u;
            }
        }

        // PV: O[q][d] += P[q][k] * Vt[d][k]^T, plus l[q] += P[q][k]*1 on the
        // MFMA pipe (ones B-operand; output col-replicated, row = quad*4+r)
        __builtin_amdgcn_s_setprio(1);
        #pragma unroll
        for (int s = 0; s < 2; ++s) {
            bf16x8 pf = *(const bf16x8*)&Ps[w][l16][s * 32 + quad * 8];
            lacc = __builtin_amdgcn_mfma_f32_16x16x32_bf16(pf, vones, lacc, 0, 0, 0);
            #pragma unroll
            for (int dc = 0; dc < 4; ++dc) {
                bf16x8 vf = *(const bf16x8*)&Vt[dc * 16 + l16][s * 32 + quad * 8];
                o[dc] = __builtin_amdgcn_mfma_f32_16x16x32_bf16(pf, vf, o[dc], 0, 0, 0);
            }
        }
        __builtin_amdgcn_s_setprio(0);
    }

    // epilogue: write unnormalized partials; l comes straight from lacc
    // (row = quad*4+r, every l16 column identical -> l16==0 lanes write)
    u16* Ob = Opart + ((size_t)bh * NCHUNK + p) * (128 * 64);
    float* Lb = Lpart + ((size_t)bh * NCHUNK + p) * 128;
    #pragma unroll
    for (int dc = 0; dc < 4; ++dc)
        #pragma unroll
        for (int r = 0; r < 4; ++r) {
            int rl = w * 16 + quad * 4 + r;
            Ob[rl * 64 + dc * 16 + l16] = f2bf(o[dc][r]);
        }
    if (l16 == 0) {
        #pragma unroll
        for (int r = 0; r < 4; ++r)
            Lb[w * 16 + quad * 4 + r] = lacc[r];
    }
}

// ---------------- combine partials -> bf16 A (vectorized, high-parallelism) ----
// grid (SEQ/32, BSZ*NHEAD), block 256: each block does 32 rows x 64 dims.
// 512-key chunk layout: ncs(bx) = (bx>>2)+1, p0 = (a+1)*(2a+b), a=bx>>2, b=bx&3.
__global__ __launch_bounds__(256) void attn_combine_kernel(
    const u16* __restrict__ Opart, const float* __restrict__ Lpart,
    u16* __restrict__ Aout) {
    __shared__ float winv[32];
    int bh = blockIdx.y;
    int b = bh / NHEAD, h = bh % NHEAD;
    int row0 = blockIdx.x * 32;             // global q-row base
    int bx = row0 >> 7;                     // 128-row q-tile
    int aa = bx >> 2, bb = bx & 3;
    int nch = aa + 1;                       // chunks for this tile (512-key)
    int p0 = (aa + 1) * (2 * aa + bb);
    int rbase = row0 & 127;                 // row offset within the 128-tile
    int t = threadIdx.x;

    if (t < 32) {
        float L = 0.f;
        for (int c = 0; c < nch; ++c)
            L += Lpart[((size_t)bh * NCHUNK + p0 + c) * 128 + rbase + t];
        winv[t] = 1.0f / L;
    }
    __syncthreads();

    int row = t >> 3;                       // 0..31
    int d0 = (t & 7) * 8;
    int rl = rbase + row;
    float acc[8] = {};
    for (int c = 0; c < nch; ++c) {
        uint4 u = *(const uint4*)&Opart[(((size_t)bh * NCHUNK + p0 + c) * 128 + rl) * 64 + d0];
        acc[0] += __uint_as_float(u.x << 16);
        acc[1] += __uint_as_float(u.x & 0xffff0000u);
        acc[2] += __uint_as_float(u.y << 16);
        acc[3] += __uint_as_float(u.y & 0xffff0000u);
        acc[4] += __uint_as_float(u.z << 16);
        acc[5] += __uint_as_float(u.z & 0xffff0000u);
        acc[6] += __uint_as_float(u.w << 16);
        acc[7] += __uint_as_float(u.w & 0xffff0000u);
    }
    float s = winv[row];
    uint4 o;
    o.x = pk2(acc[0] * s, acc[1] * s);
    o.y = pk2(acc[2] * s, acc[3] * s);
    o.z = pk2(acc[4] * s, acc[5] * s);
    o.w = pk2(acc[6] * s, acc[7] * s);
    *(uint4*)&Aout[((size_t)b * SEQ + row0 + row) * NXC + h * HD + d0] = o;
}

// ---------------- launcher ----------------
extern "C" void kernel_launch(void* const* d_in, const int* in_sizes, int n_in,
                              void* d_out, int out_size, void* d_ws, size_t ws_size,
                              hipStream_t stream) {
    const float* hs     = (const float*)d_in[0];
    const float* amask  = (const float*)d_in[1];
    const float* w_attn = (const float*)d_in[2];
    const float* b_attn = (const float*)d_in[3];
    const float* w_proj = (const float*)d_in[4];
    const float* b_proj = (const float*)d_in[5];
    float* out = (float*)d_out;

    const int M = BSZ * SEQ;            // 4096
    char* ws = (char*)d_ws;
    auto alloc = [&](size_t bytes) {
        char* p = ws;
        ws += (bytes + 255) & ~(size_t)255;
        return p;
    };
    u16* HSbf   = (u16*)alloc((size_t)M * NXC * 2);
    u16* WaT    = (u16*)alloc((size_t)3 * NXC * NXC * 2);   // 2304 x 768
    u16* WpT    = (u16*)alloc((size_t)NXC * NXC * 2);       // 768 x 768
    u16* Qb     = (u16*)alloc((size_t)M * NXC * 2);
    u16* Kb     = (u16*)alloc((size_t)M * NXC * 2);
    u16* Vb     = (u16*)alloc((size_t)M * NXC * 2);         // natural
    u16* Vtg    = (u16*)alloc((size_t)M * NXC * 2);         // per-head [d][s]
    u16* Ab     = (u16*)alloc((size_t)M * NXC * 2);
    u16* Opart  = (u16*)alloc((size_t)BSZ * NHEAD * NCHUNK * 128 * 64 * 2);
    float* Lpart = (float*)alloc((size_t)BSZ * NHEAD * NCHUNK * 128 * 4);

    // prep: cast HS + transpose both weights, one dispatch
    prep_kernel<<<dim3(5376), dim3(256), 0, stream>>>(hs, HSbf, w_attn, WaT, w_proj, WpT);
    // qkv gemm: M=4096, N=2304, K=768 -> bf16 Q/K/V natural (K pre-scaled)
    // 1D grid, XCD-swizzled in-kernel (18N x 32M = 576 blocks)
    gemm_bt_kernel<0><<<dim3((3 * NXC / 128) * (M / 128)), dim3(256), 0, stream>>>(
        HSbf, WaT, b_attn, Qb, Kb, Vb, nullptr, M, 3 * NXC, NXC);
    // per-head V transpose (direct-reshape semantics)
    vt_kernel<<<dim3(SEQ / 64, BSZ * NHEAD), dim3(256), 0, stream>>>(Vb, Vtg);
    // attention: split-K partials (512-key chunks), then combine
    attn_mfma_kernel<<<dim3(NCHUNK, BSZ * NHEAD), dim3(512), 0, stream>>>(
        Qb, Kb, Vtg, amask, Opart, Lpart);
    attn_combine_kernel<<<dim3(SEQ / 32, BSZ * NHEAD), dim3(256), 0, stream>>>(
        Opart, Lpart, Ab);
    // proj gemm: M=4096, N=768, K=768 -> d_out fp32 (6N x 32M = 192 blocks)
    gemm_bt_kernel<1><<<dim3((NXC / 128) * (M / 128)), dim3(256), 0, stream>>>(
        Ab, WpT, b_proj, nullptr, nullptr, nullptr, out, M, NXC, NXC);
}

// Round 16
// 164.154 us; speedup vs baseline: 1.0629x; 1.0222x over previous
//
#include <hip/hip_runtime.h>
#include <hip/hip_bf16.h>

typedef unsigned short u16;
typedef short bf16x8 __attribute__((ext_vector_type(8)));
typedef float f32x4 __attribute__((ext_vector_type(4)));

#define NXC 768
#define NHEAD 12
#define SEQ 2048
#define BSZ 2
#define HD 64
#define NCHUNK 40   // sum over 16 q-tiles of ceil(128*(bx+1)/512)
#define LOG2E 1.4426950408889634f

__device__ inline u16 f2bf(float f) {
    unsigned int u = __float_as_uint(f);
    unsigned int r = u + 0x7fffu + ((u >> 16) & 1u);
    return (u16)(r >> 16);
}
__device__ inline unsigned pk2(float lo, float hi) {
    return (unsigned)f2bf(lo) | ((unsigned)f2bf(hi) << 16);
}
__device__ inline float ex2(float x) { return __builtin_amdgcn_exp2f(x); }

// async global->LDS, 16B per lane. LDS dest is wave-uniform base + lane*16.
__device__ inline void gld16(const u16* g, u16* l) {
    __builtin_amdgcn_global_load_lds(
        (const __attribute__((address_space(1))) unsigned int*)(g),
        (__attribute__((address_space(3))) unsigned int*)(l),
        16, 0, 0);
}

// ---------------- merged prep: cast HS + transpose-cast both weights --------
// grid 5376 x 256: blocks [0,3072) cast4, [3072,4800) w_attn^T, [4800,5376) w_proj^T
__global__ __launch_bounds__(256) void prep_kernel(
    const float* __restrict__ hs, u16* __restrict__ HSbf,
    const float* __restrict__ w_attn, u16* __restrict__ WaT,
    const float* __restrict__ w_proj, u16* __restrict__ WpT) {
    __shared__ float tile[32][33];
    int blk = blockIdx.x;
    int t = threadIdx.x;
    if (blk < 3072) {                       // cast: 786432 float4s
        int i = blk * 256 + t;
        float4 v = ((const float4*)hs)[i];
        ushort4 o;
        o.x = f2bf(v.x); o.y = f2bf(v.y); o.z = f2bf(v.z); o.w = f2bf(v.w);
        ((ushort4*)HSbf)[i] = o;
        return;
    }
    const float* in; u16* out; int C, cb, rb;
    if (blk < 4800) {                       // w_attn: 2304 cols x 768 rows
        int idx = blk - 3072;
        in = w_attn; out = WaT; C = 3 * NXC;
        cb = (idx % 72) * 32; rb = (idx / 72) * 32;
    } else {                                // w_proj: 768 x 768
        int idx = blk - 4800;
        in = w_proj; out = WpT; C = NXC;
        cb = (idx % 24) * 32; rb = (idx / 24) * 32;
    }
    int tx = t & 31, ty = t >> 5;           // (32,8) decomposition
    #pragma unroll
    for (int i = 0; i < 32; i += 8)
        tile[ty + i][tx] = in[(size_t)(rb + ty + i) * C + cb + tx];
    __syncthreads();
    #pragma unroll
    for (int i = 0; i < 32; i += 8)
        out[(size_t)(cb + ty + i) * NXC + rb + tx] = f2bf(tile[tx][ty + i]);
}

// per-head transpose: Vb head-chunk [ss][dd] -> Vtg [dd][ss] (both bf16).
// NOTE: interprets Vb's flat memory as [b*12+h][s][d] — matches the
// reference's DIRECT reshape semantics. Do not fuse into the GEMM epilogue.
__global__ __launch_bounds__(256) void vt_kernel(const u16* __restrict__ Vb,
                                                 u16* __restrict__ Vtg) {
    __shared__ u16 tile[64][68];
    int y = blockIdx.y;                        // b*NHEAD+h
    size_t base = (size_t)y * (SEQ * HD);
    int ss0 = blockIdx.x * 64;
    int t = threadIdx.x;
    #pragma unroll
    for (int c = t; c < 512; c += 256) {
        int r = c >> 3, col = (c & 7) * 8;
        *(uint4*)&tile[r][col] = *(const uint4*)&Vb[base + (size_t)(ss0 + r) * HD + col];
    }
    __syncthreads();
    #pragma unroll
    for (int c = t; c < 512; c += 256) {
        int dd = c >> 3, s8 = (c & 7) * 8;
        ushort4 a, bq;
        a.x = tile[s8 + 0][dd]; a.y = tile[s8 + 1][dd];
        a.z = tile[s8 + 2][dd]; a.w = tile[s8 + 3][dd];
        bq.x = tile[s8 + 4][dd]; bq.y = tile[s8 + 5][dd];
        bq.z = tile[s8 + 6][dd]; bq.w = tile[s8 + 7][dd];
        u16* dst = &Vtg[base + (size_t)dd * SEQ + ss0 + s8];
        *(ushort4*)dst = a;
        *(ushort4*)(dst + 4) = bq;
    }
}

// ---------------- GEMM: C[M][N] = A[M][K] * BT[N][K]^T + bias ----------------
// 128M x TN tile, BK=32, 256 threads = 4 waves (2x2), each wave owns
// 64 x TN/2 (4 x TN/32 16x16x32 frags). global_load_lds dwordx4 into a
// TRIPLE LDS buffer with prefetch depth 2 and counted vmcnt.
// TN=128 (qkv, 576 blocks = 2.25/CU): the r10-proven config.
// TN=64 (proj): doubles grid 192->384 blocks (0.75 -> 1.5/CU) so no CU
// idles; 3 loads/step (vmcnt 6/3/0). Per-output K-order identical ->
// bit-identical results to TN=128.
// XCD-AWARE BLOCK SWIZZLE (T1, measured -2.9us r10): each XCD owns a
// contiguous (numN/2) x (numM/4) tile region so its operand panels fit
// the 4MB per-XCD L2. EPI 0: bf16 Q, K (pre-scaled 0.125*log2e), V
// natural. EPI 1: fp32 out.
template <int EPI, int TN>
__global__ __launch_bounds__(256) void gemm_bt_kernel(
    const u16* __restrict__ A, const u16* __restrict__ BT,
    const float* __restrict__ bias,
    u16* __restrict__ outQ, u16* __restrict__ outK, u16* __restrict__ outV,
    float* __restrict__ outF,
    int M, int N, int K) {
    constexpr int NJ = TN / 32;            // B frags per wave: 4 or 2
    constexpr int NB = TN / 64;            // 64-row B halves: 2 or 1
    constexpr int ABUF = 128 * 32;         // u16 per A buffer
    constexpr int BBUF = TN * 32;          // u16 per B buffer
    __shared__ u16 As[3 * ABUF];
    __shared__ u16 Bs[3 * BBUF];
    int numN = N / TN, numM = M >> 7;
    int nPer = numN >> 1, mPer = numM >> 2;    // 2(N) x 4(M) XCD split
    int wgid = blockIdx.x;
    int xcd = wgid & 7, local = wgid >> 3;
    int nloc = local % nPer, mloc = local / nPer;
    int tileN = (((xcd & 1) * nPer) + nloc) * TN;
    int tileM = ((((xcd >> 1) & 3) * mPer) + mloc) << 7;
    int t = threadIdx.x;
    int lane = t & 63, wave = t >> 6;
    int wr = (wave >> 1) * 64, wc = (wave & 1) * (TN / 2);
    int quad = lane >> 4, l16 = lane & 15;
    f32x4 acc[4][NJ] = {};

    int r0 = t >> 2, c0 = (t & 3) * 8;
    const u16* Ag0 = A + (size_t)(tileM + r0) * K + c0;
    const u16* Ag1 = Ag0 + (size_t)64 * K;
    const u16* Bg0 = BT + (size_t)(tileN + r0) * K + c0;
    const u16* Bg1 = Bg0 + (size_t)64 * K;     // used only when NB==2
    u16* AsW0 = As + wave * 512;           // rows 0..63 half
    u16* AsW1 = As + 2048 + wave * 512;    // rows 64..127 half
    u16* BsW0 = Bs + wave * 512;
    u16* BsW1 = Bs + 2048 + wave * 512;    // only NB==2

    // prologue: stage tiles 0 and 1 into buffers 0 and 1
    gld16(Ag0, AsW0);
    gld16(Ag1, AsW1);
    gld16(Bg0, BsW0);
    if constexpr (NB == 2) gld16(Bg1, BsW1);
    gld16(Ag0 + 32, AsW0 + ABUF);
    gld16(Ag1 + 32, AsW1 + ABUF);
    gld16(Bg0 + 32, BsW0 + BBUF);
    if constexpr (NB == 2) gld16(Bg1 + 32, BsW1 + BBUF);

    int NT = K >> 5;                       // 24 for K=768
    for (int tt = 0; tt < NT; ++tt) {
        int cur = tt % 3;
        if (tt + 2 < NT) {
            int kn = (tt + 2) * 32;
            int na = ((tt + 2) % 3) * ABUF;
            int nb = ((tt + 2) % 3) * BBUF;
            gld16(Ag0 + kn, AsW0 + na);
            gld16(Ag1 + kn, AsW1 + na);
            gld16(Bg0 + kn, BsW0 + nb);
            if constexpr (NB == 2) {
                gld16(Bg1 + kn, BsW1 + nb);
                asm volatile("s_waitcnt vmcnt(8)" ::: "memory");  // tile tt landed
            } else {
                asm volatile("s_waitcnt vmcnt(6)" ::: "memory");  // tile tt landed
            }
        } else if (tt + 1 < NT) {
            if constexpr (NB == 2) {
                asm volatile("s_waitcnt vmcnt(4)" ::: "memory");
            } else {
                asm volatile("s_waitcnt vmcnt(3)" ::: "memory");
            }
        } else {
            asm volatile("s_waitcnt vmcnt(0)" ::: "memory");
        }
        __builtin_amdgcn_s_barrier();          // all waves' tile-tt stage landed
        __builtin_amdgcn_sched_barrier(0);     // nothing moves above the barrier

        const u16* Ac = As + cur * ABUF;
        const u16* Bc = Bs + cur * BBUF;
        bf16x8 af[4], bfr[NJ];
        #pragma unroll
        for (int i = 0; i < 4; ++i)
            af[i] = *(const bf16x8*)&Ac[(wr + i * 16 + l16) * 32 + quad * 8];
        #pragma unroll
        for (int j = 0; j < NJ; ++j)
            bfr[j] = *(const bf16x8*)&Bc[(wc + j * 16 + l16) * 32 + quad * 8];
        #pragma unroll
        for (int i = 0; i < 4; ++i)
            #pragma unroll
            for (int j = 0; j < NJ; ++j)
                acc[i][j] = __builtin_amdgcn_mfma_f32_16x16x32_bf16(af[i], bfr[j], acc[i][j], 0, 0, 0);

        __builtin_amdgcn_sched_barrier(0);     // ds_reads stay above barrier-2
        __builtin_amdgcn_s_barrier();          // reads done before buf reuse
    }

    #pragma unroll
    for (int i = 0; i < 4; ++i) {
        #pragma unroll
        for (int j = 0; j < NJ; ++j) {
            int n = tileN + wc + j * 16 + l16;
            float bv = bias[n];
            #pragma unroll
            for (int r = 0; r < 4; ++r) {
                int m = tileM + wr + i * 16 + quad * 4 + r;
                float v = acc[i][j][r] + bv;
                if (EPI == 0) {
                    if (n < 768) {
                        outQ[(size_t)m * 768 + n] = f2bf(v);
                    } else if (n < 1536) {
                        outK[(size_t)m * 768 + (n - 768)] = f2bf(v * (0.125f * LOG2E));
                    } else {
                        outV[(size_t)m * 768 + (n - 1536)] = f2bf(v);
                    }
                } else {
                    outF[(size_t)m * N + n] = v;
                }
            }
        }
    }
}

// ---------------- MFMA flash attention, split-K (512-key chunks) ----------------
// grid (NCHUNK, BSZ*NHEAD), block 512: 8 waves x 16 q-rows. Fixed-max softmax
// in base-2 domain (K pre-scaled 0.125*log2e). Wave-uniform diag split (r14,
// -3us). MFMA l-sum via ones B-operand (r15, -1us, absmax improved).
__global__ __launch_bounds__(512) void attn_mfma_kernel(
    const u16* __restrict__ Q, const u16* __restrict__ Kg,
    const u16* __restrict__ Vtg, const float* __restrict__ amask,
    u16* __restrict__ Opart, float* __restrict__ Lpart) {
    __shared__ u16 Ks[64][72];
    __shared__ u16 Vt[64][72];          // V^T tile: [d][key]
    __shared__ u16 Ps[8][16][72];       // per-wave P [q][key]
    __shared__ float Ams[64];

    int bh = blockIdx.y;
    int b = bh / NHEAD, h = bh % NHEAD;
    int p = NCHUNK - 1 - (int)blockIdx.x;   // heavy chunks dispatch first
    int bx = 15, c = 0, a = 0;
    #pragma unroll
    for (int i = 0; i < 16; ++i) {
        int n = (i >> 2) + 1;               // chunks for q-tile i (512-key chunks)
        if (p < a + n) { bx = i; c = p - a; break; }
        a += n;
    }
    int kbase = c * 512;
    int nt = 2 * (bx + 1) - 8 * c;          // 64-key tiles in this chunk
    if (nt > 8) nt = 8;

    int t = threadIdx.x;
    int w = t >> 6, lane = t & 63;
    int quad = lane >> 4, l16 = lane & 15;
    size_t headbase = (size_t)b * (SEQ * NXC) + (size_t)h * (SEQ * HD);
    size_t headbaseT = (size_t)(b * NHEAD + h) * (SEQ * HD);

    int r0 = bx * 128;
    int qw0 = r0 + w * 16;                  // wave owns 16 q-rows
    int qrow = qw0 + l16;
    bf16x8 qf[2];
    #pragma unroll
    for (int s = 0; s < 2; ++s)
        qf[s] = *(const bf16x8*)&Q[headbase + (size_t)(qw0 + l16) * HD + s * 32 + quad * 8];

    // ones B-operand for the row-sum MFMA (bf16 1.0 = 0x3F80)
    bf16x8 vones;
    #pragma unroll
    for (int i = 0; i < 8; ++i) vones[i] = (short)0x3F80;

    f32x4 lacc = {};                        // l for q-rows quad*4+r (all l16 cols equal)
    f32x4 o[4] = {};

    // register prefetch of tile 0 (512 threads cover 64x64 K and V^T tiles)
    int pr_row = t >> 3, pr_col = (t & 7) * 8;
    uint4 kr, vr; float amr;
    {
        int k0 = kbase;
        kr = *(const uint4*)&Kg[headbase + (size_t)(k0 + pr_row) * HD + pr_col];
        vr = *(const uint4*)&Vtg[headbaseT + (size_t)pr_row * SEQ + k0 + pr_col];
        if (t < 64) amr = amask[(size_t)b * SEQ + k0 + t];
    }

    for (int kt = 0; kt < nt; ++kt) {
        int k0 = kbase + kt * 64;
        __syncthreads();
        *(uint4*)&Ks[pr_row][pr_col] = kr;
        *(uint4*)&Vt[pr_row][pr_col] = vr;
        if (t < 64) Ams[t] = amr * LOG2E;
        __syncthreads();
        if (kt + 1 < nt) {
            int kn = k0 + 64;
            kr = *(const uint4*)&Kg[headbase + (size_t)(kn + pr_row) * HD + pr_col];
            vr = *(const uint4*)&Vtg[headbaseT + (size_t)pr_row * SEQ + kn + pr_col];
            if (t < 64) amr = amask[(size_t)b * SEQ + kn + t];
        }

        if (k0 > qw0 + 15) continue;        // tile fully past-causal for this wave

        bf16x8 kf[2][4];
        #pragma unroll
        for (int s = 0; s < 2; ++s)
            #pragma unroll
            for (int j = 0; j < 4; ++j)
                kf[s][j] = *(const bf16x8*)&Ks[j * 16 + l16][s * 32 + quad * 8];
        f32x4 amv4[4];
        #pragma unroll
        for (int j = 0; j < 4; ++j)
            amv4[j] = *(const f32x4*)&Ams[j * 16 + quad * 4];

        // S^T = K * Q^T : lane owns q-row = l16
        f32x4 sacc[4] = {};
        __builtin_amdgcn_s_setprio(1);
        #pragma unroll
        for (int s = 0; s < 2; ++s)
            #pragma unroll
            for (int j = 0; j < 4; ++j)
                sacc[j] = __builtin_amdgcn_mfma_f32_16x16x32_bf16(kf[s][j], qf[s], sacc[j], 0, 0, 0);
        __builtin_amdgcn_s_setprio(0);

        if (k0 + 63 > qw0) {
            // diagonal tile (wave-uniform branch): per-element causal mask
            #pragma unroll
            for (int j = 0; j < 4; ++j) {
                float pv[4];
                #pragma unroll
                for (int r = 0; r < 4; ++r) {
                    float pp = ex2(sacc[j][r] + amv4[j][r]);
                    if (k0 + j * 16 + quad * 4 + r > qrow) pp = 0.f;
                    pv[r] = pp;
                }
                __hip_bfloat162 h01 = __float22bfloat162_rn(make_float2(pv[0], pv[1]));
                __hip_bfloat162 h23 = __float22bfloat162_rn(make_float2(pv[2], pv[3]));
                uint2 u;
                __builtin_memcpy(&u.x, &h01, 4);
                __builtin_memcpy(&u.y, &h23, 4);
                *(uint2*)&Ps[w][l16][j * 16 + quad * 4] = u;
            }
        } else {
            // fully-causal tile: maskless (bit-identical — mask was never hit)
            #pragma unroll
            for (int j = 0; j < 4; ++j) {
                float pv[4];
                #pragma unroll
                for (int r = 0; r < 4; ++r)
                    pv[r] = ex2(sacc[j][r] + amv4[j][r]);
                __hip_bfloat162 h01 = __float22bfloat162_rn(make_float2(pv[0], pv[1]));
                __hip_bfloat162 h23 = __float22bfloat162_rn(make_float2(pv[2], pv[3]));
                uint2 u;
                __builtin_memcpy(&u.x, &h01, 4);
                __builtin_memcpy(&u.y, &h23, 4);
                *(uint2*)&Ps[w][l16][j * 16 + quad * 4] = u;
            }
        }

        // PV: O[q][d] += P[q][k] * Vt[d][k]^T, plus l[q] += P[q][k]*1 on the
        // MFMA pipe (ones B-operand; output col-replicated, row = quad*4+r)
        __builtin_amdgcn_s_setprio(1);
        #pragma unroll
        for (int s = 0; s < 2; ++s) {
            bf16x8 pf = *(const bf16x8*)&Ps[w][l16][s * 32 + quad * 8];
            lacc = __builtin_amdgcn_mfma_f32_16x16x32_bf16(pf, vones, lacc, 0, 0, 0);
            #pragma unroll
            for (int dc = 0; dc < 4; ++dc) {
                bf16x8 vf = *(const bf16x8*)&Vt[dc * 16 + l16][s * 32 + quad * 8];
                o[dc] = __builtin_amdgcn_mfma_f32_16x16x32_bf16(pf, vf, o[dc], 0, 0, 0);
            }
        }
        __builtin_amdgcn_s_setprio(0);
    }

    // epilogue: write unnormalized partials; l comes straight from lacc
    // (row = quad*4+r, every l16 column identical -> l16==0 lanes write)
    u16* Ob = Opart + ((size_t)bh * NCHUNK + p) * (128 * 64);
    float* Lb = Lpart + ((size_t)bh * NCHUNK + p) * 128;
    #pragma unroll
    for (int dc = 0; dc < 4; ++dc)
        #pragma unroll
        for (int r = 0; r < 4; ++r) {
            int rl = w * 16 + quad * 4 + r;
            Ob[rl * 64 + dc * 16 + l16] = f2bf(o[dc][r]);
        }
    if (l16 == 0) {
        #pragma unroll
        for (int r = 0; r < 4; ++r)
            Lb[w * 16 + quad * 4 + r] = lacc[r];
    }
}

// ---------------- combine partials -> bf16 A (vectorized, high-parallelism) ----
// grid (SEQ/32, BSZ*NHEAD), block 256: each block does 32 rows x 64 dims.
// 512-key chunk layout: ncs(bx) = (bx>>2)+1, p0 = (a+1)*(2a+b), a=bx>>2, b=bx&3.
__global__ __launch_bounds__(256) void attn_combine_kernel(
    const u16* __restrict__ Opart, const float* __restrict__ Lpart,
    u16* __restrict__ Aout) {
    __shared__ float winv[32];
    int bh = blockIdx.y;
    int b = bh / NHEAD, h = bh % NHEAD;
    int row0 = blockIdx.x * 32;             // global q-row base
    int bx = row0 >> 7;                     // 128-row q-tile
    int aa = bx >> 2, bb = bx & 3;
    int nch = aa + 1;                       // chunks for this tile (512-key)
    int p0 = (aa + 1) * (2 * aa + bb);
    int rbase = row0 & 127;                 // row offset within the 128-tile
    int t = threadIdx.x;

    if (t < 32) {
        float L = 0.f;
        for (int c = 0; c < nch; ++c)
            L += Lpart[((size_t)bh * NCHUNK + p0 + c) * 128 + rbase + t];
        winv[t] = 1.0f / L;
    }
    __syncthreads();

    int row = t >> 3;                       // 0..31
    int d0 = (t & 7) * 8;
    int rl = rbase + row;
    float acc[8] = {};
    for (int c = 0; c < nch; ++c) {
        uint4 u = *(const uint4*)&Opart[(((size_t)bh * NCHUNK + p0 + c) * 128 + rl) * 64 + d0];
        acc[0] += __uint_as_float(u.x << 16);
        acc[1] += __uint_as_float(u.x & 0xffff0000u);
        acc[2] += __uint_as_float(u.y << 16);
        acc[3] += __uint_as_float(u.y & 0xffff0000u);
        acc[4] += __uint_as_float(u.z << 16);
        acc[5] += __uint_as_float(u.z & 0xffff0000u);
        acc[6] += __uint_as_float(u.w << 16);
        acc[7] += __uint_as_float(u.w & 0xffff0000u);
    }
    float s = winv[row];
    uint4 o;
    o.x = pk2(acc[0] * s, acc[1] * s);
    o.y = pk2(acc[2] * s, acc[3] * s);
    o.z = pk2(acc[4] * s, acc[5] * s);
    o.w = pk2(acc[6] * s, acc[7] * s);
    *(uint4*)&Aout[((size_t)b * SEQ + row0 + row) * NXC + h * HD + d0] = o;
}

// ---------------- launcher ----------------
extern "C" void kernel_launch(void* const* d_in, const int* in_sizes, int n_in,
                              void* d_out, int out_size, void* d_ws, size_t ws_size,
                              hipStream_t stream) {
    const float* hs     = (const float*)d_in[0];
    const float* amask  = (const float*)d_in[1];
    const float* w_attn = (const float*)d_in[2];
    const float* b_attn = (const float*)d_in[3];
    const float* w_proj = (const float*)d_in[4];
    const float* b_proj = (const float*)d_in[5];
    float* out = (float*)d_out;

    const int M = BSZ * SEQ;            // 4096
    char* ws = (char*)d_ws;
    auto alloc = [&](size_t bytes) {
        char* p = ws;
        ws += (bytes + 255) & ~(size_t)255;
        return p;
    };
    u16* HSbf   = (u16*)alloc((size_t)M * NXC * 2);
    u16* WaT    = (u16*)alloc((size_t)3 * NXC * NXC * 2);   // 2304 x 768
    u16* WpT    = (u16*)alloc((size_t)NXC * NXC * 2);       // 768 x 768
    u16* Qb     = (u16*)alloc((size_t)M * NXC * 2);
    u16* Kb     = (u16*)alloc((size_t)M * NXC * 2);
    u16* Vb     = (u16*)alloc((size_t)M * NXC * 2);         // natural
    u16* Vtg    = (u16*)alloc((size_t)M * NXC * 2);         // per-head [d][s]
    u16* Ab     = (u16*)alloc((size_t)M * NXC * 2);
    u16* Opart  = (u16*)alloc((size_t)BSZ * NHEAD * NCHUNK * 128 * 64 * 2);
    float* Lpart = (float*)alloc((size_t)BSZ * NHEAD * NCHUNK * 128 * 4);

    // prep: cast HS + transpose both weights, one dispatch
    prep_kernel<<<dim3(5376), dim3(256), 0, stream>>>(hs, HSbf, w_attn, WaT, w_proj, WpT);
    // qkv gemm: M=4096, N=2304, K=768 -> bf16 Q/K/V natural (K pre-scaled)
    // 1D grid, XCD-swizzled in-kernel (18N x 32M = 576 blocks, TN=128)
    gemm_bt_kernel<0, 128><<<dim3((3 * NXC / 128) * (M / 128)), dim3(256), 0, stream>>>(
        HSbf, WaT, b_attn, Qb, Kb, Vb, nullptr, M, 3 * NXC, NXC);
    // per-head V transpose (direct-reshape semantics)
    vt_kernel<<<dim3(SEQ / 64, BSZ * NHEAD), dim3(256), 0, stream>>>(Vb, Vtg);
    // attention: split-K partials (512-key chunks), then combine
    attn_mfma_kernel<<<dim3(NCHUNK, BSZ * NHEAD), dim3(512), 0, stream>>>(
        Qb, Kb, Vtg, amask, Opart, Lpart);
    attn_combine_kernel<<<dim3(SEQ / 32, BSZ * NHEAD), dim3(256), 0, stream>>>(
        Opart, Lpart, Ab);
    // proj gemm: M=4096, N=768, K=768 -> d_out fp32
    // TN=64: 12N x 32M = 384 blocks (1.5/CU, every CU occupied)
    gemm_bt_kernel<1, 64><<<dim3((NXC / 64) * (M / 128)), dim3(256), 0, stream>>>(
        Ab, WpT, b_proj, nullptr, nullptr, nullptr, out, M, NXC, NXC);
}